// Round 5
// baseline (402.587 us; speedup 1.0000x reference)
//
#include <hip/hip_runtime.h>
#include <hip/hip_bf16.h>

// Fused QKV projection + 16-head self-attention. S=2048, B=2, H=1024, NH=16, DH=64.
// Inputs fp32, output fp32. bf16 internal compute (2% rel threshold).
//
// R17 = R16 with the semaphore-init bug fixed: flags has 512 entries but the
// 256-thread cast block only zeroed [0..255] -> heads 8..15 never combined,
// out columns 512+ kept cast scratch (absmax 5.0 == max|X|). Now each thread
// zeroes two flags.
//
// R16 theory (unchanged): occupancy was structurally capped at 2 waves/SIMD
// (65536 q-rows / 32 q-per-wave); three schedule variants all landed 47-52us
// -> latency-bound. Split the 2048 keys across 2 blocks (1024 blocks = 4
// waves/SIMD; 2-deep 32KB LDS ring -> 4 blocks/CU). No-max exp2 softmax makes
// partials additive (O=O0+O1, l=l0+l1). Combine via threadfence + atomicAdd
// ticket; second finisher sums partner's partial and writes out. Guarded on
// ws_size with an NSPLIT=1 fallback identical to R15's loop.
//
// d_ws: qb 8MB | kb 8MB | vtb 8MB | po[2][hb][q][d] f32 33.5MB | lsum 0.5MB
//       | flags 2KB   (split path only; guarded by ws_size)

typedef __hip_bfloat16 bf16;
typedef __bf16 bfr;
typedef __attribute__((ext_vector_type(8))) __bf16 bf16x8;
typedef __attribute__((ext_vector_type(4))) __bf16 bf16x4;
typedef __attribute__((ext_vector_type(2))) __bf16 bf16x2;
typedef __attribute__((ext_vector_type(4))) float f32x4;
typedef __attribute__((ext_vector_type(16))) float f32x16;
typedef __attribute__((ext_vector_type(4))) unsigned u32x4;

#define S_SEQ  2048
#define HID    1024
#define OUT3   3072
#define NROWS  4096

#if __has_builtin(__builtin_amdgcn_exp2f)
#define EXP2F(x) __builtin_amdgcn_exp2f(x)
#else
#define EXP2F(x) exp2f(x)
#endif

// q pre-scale: (1/sqrt(64)) * log2(e) -> scores in base-2 domain
#define QSCALE 0.18033688011112042f

// ---------------------------------------------------------------------------
// Fused cast: fp32 -> bf16 for X then W (verified R9/R10). Block 0 also
// zeroes the 512 split-K semaphores (2 per thread; runs before attn,
// stream-ordered).
// ---------------------------------------------------------------------------
__global__ __launch_bounds__(256) void cast_both_kernel(
    const float* __restrict__ X, bfr* __restrict__ Xb,
    const float* __restrict__ W, bfr* __restrict__ Wb,
    int* flags)
{
    int bid = blockIdx.x;
    if (flags != nullptr && bid == 0) {
        flags[threadIdx.x] = 0;
        flags[threadIdx.x + 256] = 0;
    }
    const float* src;
    bfr* dst;
    int lid;
    if (bid < NROWS * HID / 2048) { src = X; dst = Xb; lid = bid; }
    else { src = W; dst = Wb; lid = bid - NROWS * HID / 2048; }
    int gid = lid * 256 + threadIdx.x;
    const float4* s4 = (const float4*)src;
    float4 a = s4[(size_t)gid * 2];
    float4 b = s4[(size_t)gid * 2 + 1];
    bf16x8 v;
    v[0] = (bfr)a.x; v[1] = (bfr)a.y; v[2] = (bfr)a.z; v[3] = (bfr)a.w;
    v[4] = (bfr)b.x; v[5] = (bfr)b.y; v[6] = (bfr)b.z; v[7] = (bfr)b.w;
    *(bf16x8*)(dst + (size_t)gid * 8) = v;
}

// ---------------------------------------------------------------------------
// MFMA GEMM (m97 recipe). Epilogue: qb (pre-scaled), kb stored directly
// (32B-contiguous per 16 lanes); vtb (V^T, the 4KB-stride case) goes through
// an LDS transpose reusing the As/Bs region, then coalesced bf16x8 stores.
// ---------------------------------------------------------------------------
__device__ __forceinline__ void gload_lds16(const void* g, void* l) {
    __builtin_amdgcn_global_load_lds(
        (const __attribute__((address_space(1))) unsigned int*)g,
        (__attribute__((address_space(3))) unsigned int*)l, 16, 0, 0);
}

__global__ __launch_bounds__(256, 3) void qkv_gemm_mfma(
    const bfr* __restrict__ Xb, const bfr* __restrict__ Wb,
    const float* __restrict__ bias,
    bfr* __restrict__ qb, bfr* __restrict__ kb, bfr* __restrict__ vtb)
{
    __shared__ __attribute__((aligned(16))) unsigned char lds_all[32768];
    bfr* As = (bfr*)lds_all;              // 128x64 bf16 = 16384 B
    bfr* Bs = (bfr*)(lds_all + 16384);    // 128x64 bf16 = 16384 B
    bfr* Tr = (bfr*)lds_all;              // epilogue V^T buf: 64 x 144 = 18432 B

    const int o0 = blockIdx.x * 128;
    const int r0 = blockIdx.y * 128;
    const int tid = threadIdx.x;
    const int lane = tid & 63;
    const int w = tid >> 6;
    const int l15 = lane & 15;
    const int quad = lane >> 4;
    const int m0 = (w & 1) * 64;
    const int n0 = (w >> 1) * 64;

    f32x4 acc[4][4];
#pragma unroll
    for (int mi = 0; mi < 4; mi++)
#pragma unroll
        for (int ni = 0; ni < 4; ni++) acc[mi][ni] = {0.f, 0.f, 0.f, 0.f};

    for (int k0 = 0; k0 < HID; k0 += 64) {
#pragma unroll
        for (int i = 0; i < 4; i++) {
            int c = i * 256 + tid;
            int row = c >> 3, c8 = c & 7;
            gload_lds16(Xb + (size_t)(r0 + row) * HID + k0 + c8 * 8, As + c * 8);
            gload_lds16(Wb + (size_t)(o0 + row) * HID + k0 + c8 * 8, Bs + c * 8);
        }
        __syncthreads();

#pragma unroll
        for (int ks = 0; ks < 2; ks++) {
            bf16x8 af[4], bfg[4];
#pragma unroll
            for (int mi = 0; mi < 4; mi++)
                af[mi] = *(const bf16x8*)(As + (m0 + mi * 16 + l15) * 64 + ks * 32 + quad * 8);
#pragma unroll
            for (int ni = 0; ni < 4; ni++)
                bfg[ni] = *(const bf16x8*)(Bs + (n0 + ni * 16 + l15) * 64 + ks * 32 + quad * 8);
#pragma unroll
            for (int mi = 0; mi < 4; mi++)
#pragma unroll
                for (int ni = 0; ni < 4; ni++)
                    acc[mi][ni] = __builtin_amdgcn_mfma_f32_16x16x32_bf16(
                        af[mi], bfg[ni], acc[mi][ni], 0, 0, 0);
        }
        __syncthreads();   // also makes As/Bs safe to reuse as Tr after loop
    }

    // --- epilogue. C/D layout: col=l15, row=quad*4+r.
    const int omod = o0 % 192;
#pragma unroll
    for (int ni = 0; ni < 4; ni++) {
        int cb = o0 + n0 + ni * 16;
        int h = cb / 192;
        int rem = cb % 192;
        int t = rem >> 6;
        int d = (rem & 63) + l15;
        float bv = bias[cb + l15];
        if (t == 2) {
#pragma unroll
            for (int mi = 0; mi < 4; mi++)
#pragma unroll
                for (int r = 0; r < 4; r++) {
                    int grl = m0 + mi * 16 + quad * 4 + r;   // 0..127
                    Tr[(size_t)d * 144 + (grl & 1) * 72 + (grl >> 1)]
                        = (bfr)(acc[mi][ni][r] + bv);
                }
        } else {
#pragma unroll
            for (int mi = 0; mi < 4; mi++)
#pragma unroll
                for (int r = 0; r < 4; r++) {
                    int gr = r0 + m0 + mi * 16 + quad * 4 + r;
                    int s = gr >> 1, b = gr & 1;
                    int hb = h * 2 + b;
                    float val = acc[mi][ni][r] + bv;
                    if (t == 0)
                        qb[((size_t)hb * S_SEQ + s) * 64 + d] = (bfr)(val * QSCALE);
                    else
                        kb[((size_t)hb * S_SEQ + s) * 64 + d] = (bfr)val;
                }
        }
    }
    if (omod != 0) {          // block-uniform: this block produced a V tile
        __syncthreads();      // Tr writes visible
        int ht = (omod == 64) ? (o0 + 64) / 192 : o0 / 192;
        int d = tid >> 2;
        int b = (tid >> 1) & 1;
        int chunk = tid & 1;            // 32-s half
        int s0 = r0 >> 1;
        int hb = ht * 2 + b;
        const bfr* src = Tr + (size_t)d * 144 + b * 72 + chunk * 32;
        bfr* dstp = vtb + ((size_t)hb * 64 + d) * S_SEQ + s0 + chunk * 32;
#pragma unroll
        for (int j = 0; j < 4; j++)
            *(bf16x8*)(dstp + j * 8) = *(const bf16x8*)(src + j * 8);
    }
}

// ---------------------------------------------------------------------------
// Attention, 32x32x16 MFMA, split-K over keys (NSPLIT blocks per (qt,hb)).
// Block = 4 waves x 32 q = 128 q rows. NSPLIT=2: grid (32, 32), each block
// does 16 of the 32 64-key tiles; NSPLIT=1: grid (16, 32), all 32 tiles.
//   S^T = K*Q^T : A=K rows (lane&31=key), B=Q^T regs (lane&31=q).
//   C/D: col=lane&31=q, row(key)=(r&3)+8*(r>>2)+4*(lane>>5).
//   softmax in-register: exp2 + bf16 pair-pack + v_permlane32_swap_b32.
//   O^T += V^T*P^T : A=V^T rows (lane&31=d).
// LDS: 2-deep ring of {K[64][64], V^T[64][64]} bf16 = 32 KB; linear 128B rows;
// XOR swizzle slot = chunk16B ^ (row&7) on the global source AND the ds_read
// address (rule 21). Schedule per tile t: vmcnt(0); barrier; STAGE(t+1);
// compute(t).  Stage(t+1) targets buf (t+1)&1, last read at t-1 (barrier-
// proven done); the vmcnt at t+1 waits loads issued one compute phase ago.
// Split epilogue: write unnormalized partial O/lsum to own slot; threadfence;
// syncthreads; t0 atomicAdd(pair flag); second finisher reads partner slot,
// sums, normalizes, writes out (device-scope fence per G16).
// ---------------------------------------------------------------------------
__device__ __forceinline__ void plswap(unsigned &a, unsigned &b) {
    asm volatile("v_permlane32_swap_b32 %0, %1" : "+v"(a), "+v"(b));
}

template<int NSPLIT>
__global__ __launch_bounds__(256, 4) void attn32_kernel(
    const bfr* __restrict__ qb, const bfr* __restrict__ kb,
    const bfr* __restrict__ vtb,
    float* po, float* lsumP, int* flags,
    float* __restrict__ out)
{
    // [buf][K=0/V=1][row*64 + elem]; 2 * 2 * 8KB = 32KB
    __shared__ __attribute__((aligned(16))) bfr KV[2][2][64 * 64];

    constexpr int NT = 32 / NSPLIT;      // 64-key tiles per block
    const int qt    = (NSPLIT == 2) ? (blockIdx.x >> 1) : blockIdx.x;
    const int split = (NSPLIT == 2) ? (blockIdx.x & 1) : 0;
    const int tbase = split * NT;
    const int hb = blockIdx.y;
    const int h = hb >> 1, b = hb & 1;
    const int tid = threadIdx.x;
    const int lane = tid & 63;
    const int w = tid >> 6;
    const int l31 = lane & 31;
    const int hi = lane >> 5;
    const size_t hboff = (size_t)hb * S_SEQ * 64;

    const int srow = tid >> 3;           // staging row (0..31), +32 for i=1
    const int slot = tid & 7;            // 16B slot within the 128B row

    const int qrow = qt * 128 + w * 32 + l31;
    bf16x8 qf[4];                        // B-frags: k=d in [kk*16+hi*8, +8)
#pragma unroll
    for (int kk = 0; kk < 4; kk++)
        qf[kk] = *(const bf16x8*)(qb + hboff + (size_t)qrow * 64 + kk * 16 + hi * 8);

    f32x16 Oacc[2];
#pragma unroll
    for (int dt = 0; dt < 2; dt++)
#pragma unroll
        for (int i = 0; i < 16; i++) Oacc[dt][i] = 0.f;
    float lsum = 0.f;                    // per-lane partial (own keys only)

    // Stage local tile lt (global tile tbase+lt) into buf lt&1.
    // LDS dest linear (tid*16B); global chunk gc = slot ^ (row&7).
#define STAGE(lt_) do {                                                        \
    int lt__ = (lt_); int kt__ = tbase + lt__; int bf__ = lt__ & 1;            \
    _Pragma("unroll")                                                          \
    for (int i = 0; i < 2; i++) {                                              \
        int r = i * 32 + srow;                                                 \
        int gc = slot ^ (r & 7);                                               \
        gload_lds16(kb + hboff + (size_t)(kt__ * 64 + r) * 64 + gc * 8,        \
                    (bfr*)&KV[bf__][0][0] + i * 2048 + tid * 8);               \
    }                                                                          \
    _Pragma("unroll")                                                          \
    for (int i = 0; i < 2; i++) {                                              \
        int r = i * 32 + srow;                                                 \
        int gc = slot ^ (r & 7);                                               \
        gload_lds16(vtb + hboff + (size_t)r * S_SEQ + kt__ * 64 + gc * 8,      \
                    (bfr*)&KV[bf__][1][0] + i * 2048 + tid * 8);               \
    }                                                                          \
} while (0)

    STAGE(0);

    for (int t = 0; t < NT; t++) {
        // Loads for tile t issued one compute phase ago (prologue for t=0).
        asm volatile("s_waitcnt vmcnt(0)" ::: "memory");
        __builtin_amdgcn_s_barrier();    // + proves buf (t+1)&1 reads done
        if (t + 1 < NT) STAGE(t + 1);

        const bfr* Kb = &KV[t & 1][0][0];
        const bfr* Vb = &KV[t & 1][1][0];

        // --- S^T = K Q^T (base-2 domain), 2 key-subtiles of 32 ---
        unsigned wds[2][8];   // packed bf16 pairs
        float rs = 0.f;
#pragma unroll
        for (int ts = 0; ts < 2; ts++) {
            const int krow = ts * 32 + l31;
            f32x16 sc;
#pragma unroll
            for (int i = 0; i < 16; i++) sc[i] = 0.f;
#pragma unroll
            for (int kk = 0; kk < 4; kk++) {
                int ks = (kk * 2 + hi) ^ (krow & 7);
                bf16x8 kf = *(const bf16x8*)(Kb + krow * 64 + ks * 8);
                sc = __builtin_amdgcn_mfma_f32_32x32x16_bf16(kf, qf[kk], sc, 0, 0, 0);
            }
            // keys(r) = (r&3) + 8*(r>>2) + 4*hi; pairs r=2a,2a+1 contiguous
#pragma unroll
            for (int a = 0; a < 8; a++) {
                float p0 = EXP2F(sc[2 * a]);
                float p1 = EXP2F(sc[2 * a + 1]);
                rs += p0 + p1;
                bf16x2 pk; pk[0] = (bfr)p0; pk[1] = (bfr)p1;
                wds[ts][a] = __builtin_bit_cast(unsigned, pk);
            }
        }
        lsum += rs;

        // --- redistribute into PV B-frags: swap(w[a], w[a+2]) fills two words
        bf16x8 pfrag[4];
#pragma unroll
        for (int c = 0; c < 4; c++) {
            int ts = c >> 1, cc = c & 1;
            unsigned w0 = wds[ts][cc * 4 + 0];
            unsigned w1 = wds[ts][cc * 4 + 1];
            unsigned w2 = wds[ts][cc * 4 + 2];
            unsigned w3 = wds[ts][cc * 4 + 3];
            plswap(w0, w2);   // -> frag words 0 and 2
            plswap(w1, w3);   // -> frag words 1 and 3
            u32x4 pw; pw[0] = w0; pw[1] = w1; pw[2] = w2; pw[3] = w3;
            pfrag[c] = __builtin_bit_cast(bf16x8, pw);
        }

        // --- O^T += V^T P^T ---
#pragma unroll
        for (int kk = 0; kk < 4; kk++)
#pragma unroll
            for (int dt = 0; dt < 2; dt++) {
                int vrow = dt * 32 + l31;
                int vs = (kk * 2 + hi) ^ (vrow & 7);
                bf16x8 vf = *(const bf16x8*)(Vb + vrow * 64 + vs * 8);
                Oacc[dt] = __builtin_amdgcn_mfma_f32_32x32x16_bf16(vf, pfrag[kk], Oacc[dt], 0, 0, 0);
            }
    }
#undef STAGE

    // --- epilogue: O^T[d][q]; d = dt*32 + 8*g + 4*hi + 0..3 per lane q=qrow.
    lsum += __shfl_xor(lsum, 32);        // combine the two key-halves

    if constexpr (NSPLIT == 1) {
        float inv = 1.0f / lsum;
        float* orow = out + ((size_t)qrow * 2 + b) * HID + h * 64;
#pragma unroll
        for (int dt = 0; dt < 2; dt++)
#pragma unroll
            for (int g = 0; g < 4; g++) {
                float4 o4;
                o4.x = Oacc[dt][4 * g + 0] * inv;
                o4.y = Oacc[dt][4 * g + 1] * inv;
                o4.z = Oacc[dt][4 * g + 2] * inv;
                o4.w = Oacc[dt][4 * g + 3] * inv;
                *(float4*)(orow + dt * 32 + 8 * g + 4 * hi) = o4;
            }
    } else {
        // Write own unnormalized partial to slot [split].
        float* prow = po + (((size_t)split * 32 + hb) * S_SEQ + qrow) * 64;
#pragma unroll
        for (int dt = 0; dt < 2; dt++)
#pragma unroll
            for (int g = 0; g < 4; g++) {
                float4 o4;
                o4.x = Oacc[dt][4 * g + 0];
                o4.y = Oacc[dt][4 * g + 1];
                o4.z = Oacc[dt][4 * g + 2];
                o4.w = Oacc[dt][4 * g + 3];
                *(float4*)(prow + dt * 32 + 8 * g + 4 * hi) = o4;
            }
        if (hi == 0)
            lsumP[((size_t)split * 32 + hb) * S_SEQ + qrow] = lsum;
        __threadfence();                 // release own partial (device scope)
        __syncthreads();
        __shared__ int role;
        if (tid == 0) role = atomicAdd(&flags[hb * 16 + qt], 1);
        __syncthreads();
        if (role == 1) {                 // second finisher: combine + store
            __threadfence();             // acquire partner partial
            const float* qrow2 =
                po + (((size_t)(1 - split) * 32 + hb) * S_SEQ + qrow) * 64;
            float l2 = lsumP[((size_t)(1 - split) * 32 + hb) * S_SEQ + qrow];
            float inv = 1.0f / (lsum + l2);
            float* orow = out + ((size_t)qrow * 2 + b) * HID + h * 64;
#pragma unroll
            for (int dt = 0; dt < 2; dt++)
#pragma unroll
                for (int g = 0; g < 4; g++) {
                    int off = dt * 32 + 8 * g + 4 * hi;
                    float4 p = *(const float4*)(qrow2 + off);
                    float4 o4;
                    o4.x = (Oacc[dt][4 * g + 0] + p.x) * inv;
                    o4.y = (Oacc[dt][4 * g + 1] + p.y) * inv;
                    o4.z = (Oacc[dt][4 * g + 2] + p.z) * inv;
                    o4.w = (Oacc[dt][4 * g + 3] + p.w) * inv;
                    *(float4*)(orow + off) = o4;
                }
        }
    }
}

// ---------------------------------------------------------------------------
extern "C" void kernel_launch(void* const* d_in, const int* in_sizes, int n_in,
                              void* d_out, int out_size, void* d_ws, size_t ws_size,
                              hipStream_t stream) {
    const float* X    = (const float*)d_in[0];
    const float* W    = (const float*)d_in[1];
    const float* bias = (const float*)d_in[2];
    float* out = (float*)d_out;

    bfr* qb  = (bfr*)d_ws;
    bfr* kb  = qb + (size_t)32 * S_SEQ * 64;
    bfr* vtb = kb + (size_t)32 * S_SEQ * 64;

    // Split-K scratch (beyond the 24MB qkv region):
    //   po   [2][32][2048][64] f32 = 33.55 MB
    //   lsum [2][32][2048]     f32 =  0.52 MB
    //   flags[512]             int =  2 KB
    const size_t qkv_bytes = (size_t)3 * 32 * S_SEQ * 64 * 2;        // 25165824
    const size_t po_elems  = (size_t)2 * 32 * S_SEQ * 64;
    const size_t ls_elems  = (size_t)2 * 32 * S_SEQ;
    const size_t need = qkv_bytes + po_elems * 4 + ls_elems * 4 + 512 * 4;
    const bool use_split = ws_size >= need;

    float* po    = (float*)((char*)d_ws + qkv_bytes);
    float* lsumP = po + po_elems;
    int*   flags = (int*)(lsumP + ls_elems);

    // d_out as cast scratch (14.7 MB <= 16.8 MB); attention overwrites it last.
    bfr* Xb = (bfr*)d_out;
    bfr* Wb = Xb + (size_t)NROWS * HID;

    cast_both_kernel<<<(NROWS * HID + OUT3 * HID) / 2048, 256, 0, stream>>>(
        X, Xb, W, Wb, use_split ? flags : nullptr);

    dim3 g1(OUT3 / 128, NROWS / 128);           // 24 x 32 = 768 blocks
    qkv_gemm_mfma<<<g1, 256, 0, stream>>>(Xb, Wb, bias, qb, kb, vtb);

    if (use_split) {
        dim3 g2(S_SEQ / 64, 32);                // 32 x 32 = 1024 blocks
        attn32_kernel<2><<<g2, 256, 0, stream>>>(qb, kb, vtb, po, lsumP, flags, out);
    } else {
        dim3 g2(S_SEQ / 128, 32);               // 16 x 32 = 512 blocks
        attn32_kernel<1><<<g2, 256, 0, stream>>>(qb, kb, vtb, nullptr, nullptr, nullptr, out);
    }
}

// Round 6
// 401.077 us; speedup vs baseline: 1.0038x; 1.0038x over previous
//
#include <hip/hip_runtime.h>
#include <hip/hip_bf16.h>

// Fused QKV projection + 16-head self-attention. S=2048, B=2, H=1024, NH=16, DH=64.
// Inputs fp32, output fp32. bf16 internal compute (2% rel threshold).
//
// R18 = R17 with ONE change: attn __launch_bounds__ restored to (256, 2).
// R17's (256, 4) made the allocator cram the ~90-reg live set into 64 VGPRs
// -> accumulator spills to scratch in the inner loop -> 310us with all pipes
// <6% busy. At 88 VGPR (<=128 step) + 33KB LDS the hardware still reaches
// 4 blocks/CU -- the occupancy the split-K was designed to buy.
//
// R16 theory (still the live hypothesis, now actually being tested):
// occupancy was structurally capped at 2 waves/SIMD (65536 q-rows / 32 q per
// wave); split the 2048 keys across 2 blocks (1024 blocks -> 4 waves/SIMD).
// No-max exp2 softmax makes partials additive (O=O0+O1, l=l0+l1). Combine via
// threadfence + atomicAdd ticket; second finisher sums partner's partial and
// writes out. Guarded on ws_size with an NSPLIT=1 fallback (R15's loop).
//
// d_ws: qb 8MB | kb 8MB | vtb 8MB | po[2][hb][q][d] f32 33.5MB | lsum 0.5MB
//       | flags 2KB   (split path only; guarded by ws_size)

typedef __hip_bfloat16 bf16;
typedef __bf16 bfr;
typedef __attribute__((ext_vector_type(8))) __bf16 bf16x8;
typedef __attribute__((ext_vector_type(4))) __bf16 bf16x4;
typedef __attribute__((ext_vector_type(2))) __bf16 bf16x2;
typedef __attribute__((ext_vector_type(4))) float f32x4;
typedef __attribute__((ext_vector_type(16))) float f32x16;
typedef __attribute__((ext_vector_type(4))) unsigned u32x4;

#define S_SEQ  2048
#define HID    1024
#define OUT3   3072
#define NROWS  4096

#if __has_builtin(__builtin_amdgcn_exp2f)
#define EXP2F(x) __builtin_amdgcn_exp2f(x)
#else
#define EXP2F(x) exp2f(x)
#endif

// q pre-scale: (1/sqrt(64)) * log2(e) -> scores in base-2 domain
#define QSCALE 0.18033688011112042f

// ---------------------------------------------------------------------------
// Fused cast: fp32 -> bf16 for X then W (verified R9/R10). Block 0 also
// zeroes the 512 split-K semaphores (2 per thread; runs before attn,
// stream-ordered).
// ---------------------------------------------------------------------------
__global__ __launch_bounds__(256) void cast_both_kernel(
    const float* __restrict__ X, bfr* __restrict__ Xb,
    const float* __restrict__ W, bfr* __restrict__ Wb,
    int* flags)
{
    int bid = blockIdx.x;
    if (flags != nullptr && bid == 0) {
        flags[threadIdx.x] = 0;
        flags[threadIdx.x + 256] = 0;
    }
    const float* src;
    bfr* dst;
    int lid;
    if (bid < NROWS * HID / 2048) { src = X; dst = Xb; lid = bid; }
    else { src = W; dst = Wb; lid = bid - NROWS * HID / 2048; }
    int gid = lid * 256 + threadIdx.x;
    const float4* s4 = (const float4*)src;
    float4 a = s4[(size_t)gid * 2];
    float4 b = s4[(size_t)gid * 2 + 1];
    bf16x8 v;
    v[0] = (bfr)a.x; v[1] = (bfr)a.y; v[2] = (bfr)a.z; v[3] = (bfr)a.w;
    v[4] = (bfr)b.x; v[5] = (bfr)b.y; v[6] = (bfr)b.z; v[7] = (bfr)b.w;
    *(bf16x8*)(dst + (size_t)gid * 8) = v;
}

// ---------------------------------------------------------------------------
// MFMA GEMM (m97 recipe). Epilogue: qb (pre-scaled), kb stored directly
// (32B-contiguous per 16 lanes); vtb (V^T, the 4KB-stride case) goes through
// an LDS transpose reusing the As/Bs region, then coalesced bf16x8 stores.
// ---------------------------------------------------------------------------
__device__ __forceinline__ void gload_lds16(const void* g, void* l) {
    __builtin_amdgcn_global_load_lds(
        (const __attribute__((address_space(1))) unsigned int*)g,
        (__attribute__((address_space(3))) unsigned int*)l, 16, 0, 0);
}

__global__ __launch_bounds__(256, 3) void qkv_gemm_mfma(
    const bfr* __restrict__ Xb, const bfr* __restrict__ Wb,
    const float* __restrict__ bias,
    bfr* __restrict__ qb, bfr* __restrict__ kb, bfr* __restrict__ vtb)
{
    __shared__ __attribute__((aligned(16))) unsigned char lds_all[32768];
    bfr* As = (bfr*)lds_all;              // 128x64 bf16 = 16384 B
    bfr* Bs = (bfr*)(lds_all + 16384);    // 128x64 bf16 = 16384 B
    bfr* Tr = (bfr*)lds_all;              // epilogue V^T buf: 64 x 144 = 18432 B

    const int o0 = blockIdx.x * 128;
    const int r0 = blockIdx.y * 128;
    const int tid = threadIdx.x;
    const int lane = tid & 63;
    const int w = tid >> 6;
    const int l15 = lane & 15;
    const int quad = lane >> 4;
    const int m0 = (w & 1) * 64;
    const int n0 = (w >> 1) * 64;

    f32x4 acc[4][4];
#pragma unroll
    for (int mi = 0; mi < 4; mi++)
#pragma unroll
        for (int ni = 0; ni < 4; ni++) acc[mi][ni] = {0.f, 0.f, 0.f, 0.f};

    for (int k0 = 0; k0 < HID; k0 += 64) {
#pragma unroll
        for (int i = 0; i < 4; i++) {
            int c = i * 256 + tid;
            int row = c >> 3, c8 = c & 7;
            gload_lds16(Xb + (size_t)(r0 + row) * HID + k0 + c8 * 8, As + c * 8);
            gload_lds16(Wb + (size_t)(o0 + row) * HID + k0 + c8 * 8, Bs + c * 8);
        }
        __syncthreads();

#pragma unroll
        for (int ks = 0; ks < 2; ks++) {
            bf16x8 af[4], bfg[4];
#pragma unroll
            for (int mi = 0; mi < 4; mi++)
                af[mi] = *(const bf16x8*)(As + (m0 + mi * 16 + l15) * 64 + ks * 32 + quad * 8);
#pragma unroll
            for (int ni = 0; ni < 4; ni++)
                bfg[ni] = *(const bf16x8*)(Bs + (n0 + ni * 16 + l15) * 64 + ks * 32 + quad * 8);
#pragma unroll
            for (int mi = 0; mi < 4; mi++)
#pragma unroll
                for (int ni = 0; ni < 4; ni++)
                    acc[mi][ni] = __builtin_amdgcn_mfma_f32_16x16x32_bf16(
                        af[mi], bfg[ni], acc[mi][ni], 0, 0, 0);
        }
        __syncthreads();   // also makes As/Bs safe to reuse as Tr after loop
    }

    // --- epilogue. C/D layout: col=l15, row=quad*4+r.
    const int omod = o0 % 192;
#pragma unroll
    for (int ni = 0; ni < 4; ni++) {
        int cb = o0 + n0 + ni * 16;
        int h = cb / 192;
        int rem = cb % 192;
        int t = rem >> 6;
        int d = (rem & 63) + l15;
        float bv = bias[cb + l15];
        if (t == 2) {
#pragma unroll
            for (int mi = 0; mi < 4; mi++)
#pragma unroll
                for (int r = 0; r < 4; r++) {
                    int grl = m0 + mi * 16 + quad * 4 + r;   // 0..127
                    Tr[(size_t)d * 144 + (grl & 1) * 72 + (grl >> 1)]
                        = (bfr)(acc[mi][ni][r] + bv);
                }
        } else {
#pragma unroll
            for (int mi = 0; mi < 4; mi++)
#pragma unroll
                for (int r = 0; r < 4; r++) {
                    int gr = r0 + m0 + mi * 16 + quad * 4 + r;
                    int s = gr >> 1, b = gr & 1;
                    int hb = h * 2 + b;
                    float val = acc[mi][ni][r] + bv;
                    if (t == 0)
                        qb[((size_t)hb * S_SEQ + s) * 64 + d] = (bfr)(val * QSCALE);
                    else
                        kb[((size_t)hb * S_SEQ + s) * 64 + d] = (bfr)val;
                }
        }
    }
    if (omod != 0) {          // block-uniform: this block produced a V tile
        __syncthreads();      // Tr writes visible
        int ht = (omod == 64) ? (o0 + 64) / 192 : o0 / 192;
        int d = tid >> 2;
        int b = (tid >> 1) & 1;
        int chunk = tid & 1;            // 32-s half
        int s0 = r0 >> 1;
        int hb = ht * 2 + b;
        const bfr* src = Tr + (size_t)d * 144 + b * 72 + chunk * 32;
        bfr* dstp = vtb + ((size_t)hb * 64 + d) * S_SEQ + s0 + chunk * 32;
#pragma unroll
        for (int j = 0; j < 4; j++)
            *(bf16x8*)(dstp + j * 8) = *(const bf16x8*)(src + j * 8);
    }
}

// ---------------------------------------------------------------------------
// Attention, 32x32x16 MFMA, split-K over keys (NSPLIT blocks per (qt,hb)).
// Block = 4 waves x 32 q = 128 q rows. NSPLIT=2: grid (32, 32), each block
// does 16 of the 32 64-key tiles; NSPLIT=1: grid (16, 32), all 32 tiles.
//   S^T = K*Q^T : A=K rows (lane&31=key), B=Q^T regs (lane&31=q).
//   C/D: col=lane&31=q, row(key)=(r&3)+8*(r>>2)+4*(lane>>5).
//   softmax in-register: exp2 + bf16 pair-pack + v_permlane32_swap_b32.
//   O^T += V^T*P^T : A=V^T rows (lane&31=d).
// LDS: 2-deep ring of {K[64][64], V^T[64][64]} bf16 = 32 KB; linear 128B rows;
// XOR swizzle slot = chunk16B ^ (row&7) on the global source AND the ds_read
// address (rule 21). Schedule per tile t: vmcnt(0); barrier; STAGE(t+1);
// compute(t).
// Split epilogue: write unnormalized partial O/lsum to own slot; threadfence;
// syncthreads; t0 atomicAdd(pair flag); second finisher reads partner slot,
// sums, normalizes, writes out (device-scope fence per G16).
// ---------------------------------------------------------------------------
__device__ __forceinline__ void plswap(unsigned &a, unsigned &b) {
    asm volatile("v_permlane32_swap_b32 %0, %1" : "+v"(a), "+v"(b));
}

template<int NSPLIT>
__global__ __launch_bounds__(256, 2) void attn32_kernel(
    const bfr* __restrict__ qb, const bfr* __restrict__ kb,
    const bfr* __restrict__ vtb,
    float* po, float* lsumP, int* flags,
    float* __restrict__ out)
{
    // [buf][K=0/V=1][row*64 + elem]; 2 * 2 * 8KB = 32KB
    __shared__ __attribute__((aligned(16))) bfr KV[2][2][64 * 64];

    constexpr int NT = 32 / NSPLIT;      // 64-key tiles per block
    const int qt    = (NSPLIT == 2) ? (blockIdx.x >> 1) : blockIdx.x;
    const int split = (NSPLIT == 2) ? (blockIdx.x & 1) : 0;
    const int tbase = split * NT;
    const int hb = blockIdx.y;
    const int h = hb >> 1, b = hb & 1;
    const int tid = threadIdx.x;
    const int lane = tid & 63;
    const int w = tid >> 6;
    const int l31 = lane & 31;
    const int hi = lane >> 5;
    const size_t hboff = (size_t)hb * S_SEQ * 64;

    const int srow = tid >> 3;           // staging row (0..31), +32 for i=1
    const int slot = tid & 7;            // 16B slot within the 128B row

    const int qrow = qt * 128 + w * 32 + l31;
    bf16x8 qf[4];                        // B-frags: k=d in [kk*16+hi*8, +8)
#pragma unroll
    for (int kk = 0; kk < 4; kk++)
        qf[kk] = *(const bf16x8*)(qb + hboff + (size_t)qrow * 64 + kk * 16 + hi * 8);

    f32x16 Oacc[2];
#pragma unroll
    for (int dt = 0; dt < 2; dt++)
#pragma unroll
        for (int i = 0; i < 16; i++) Oacc[dt][i] = 0.f;
    float lsum = 0.f;                    // per-lane partial (own keys only)

    // Stage local tile lt (global tile tbase+lt) into buf lt&1.
    // LDS dest linear (tid*16B); global chunk gc = slot ^ (row&7).
#define STAGE(lt_) do {                                                        \
    int lt__ = (lt_); int kt__ = tbase + lt__; int bf__ = lt__ & 1;            \
    _Pragma("unroll")                                                          \
    for (int i = 0; i < 2; i++) {                                              \
        int r = i * 32 + srow;                                                 \
        int gc = slot ^ (r & 7);                                               \
        gload_lds16(kb + hboff + (size_t)(kt__ * 64 + r) * 64 + gc * 8,        \
                    (bfr*)&KV[bf__][0][0] + i * 2048 + tid * 8);               \
    }                                                                          \
    _Pragma("unroll")                                                          \
    for (int i = 0; i < 2; i++) {                                              \
        int r = i * 32 + srow;                                                 \
        int gc = slot ^ (r & 7);                                               \
        gload_lds16(vtb + hboff + (size_t)r * S_SEQ + kt__ * 64 + gc * 8,      \
                    (bfr*)&KV[bf__][1][0] + i * 2048 + tid * 8);               \
    }                                                                          \
} while (0)

    STAGE(0);

    for (int t = 0; t < NT; t++) {
        // Loads for tile t issued one compute phase ago (prologue for t=0).
        asm volatile("s_waitcnt vmcnt(0)" ::: "memory");
        __builtin_amdgcn_s_barrier();    // + proves buf (t+1)&1 reads done
        if (t + 1 < NT) STAGE(t + 1);

        const bfr* Kb = &KV[t & 1][0][0];
        const bfr* Vb = &KV[t & 1][1][0];

        // --- S^T = K Q^T (base-2 domain), 2 key-subtiles of 32 ---
        unsigned wds[2][8];   // packed bf16 pairs
        float rs = 0.f;
#pragma unroll
        for (int ts = 0; ts < 2; ts++) {
            const int krow = ts * 32 + l31;
            f32x16 sc;
#pragma unroll
            for (int i = 0; i < 16; i++) sc[i] = 0.f;
#pragma unroll
            for (int kk = 0; kk < 4; kk++) {
                int ks = (kk * 2 + hi) ^ (krow & 7);
                bf16x8 kf = *(const bf16x8*)(Kb + krow * 64 + ks * 8);
                sc = __builtin_amdgcn_mfma_f32_32x32x16_bf16(kf, qf[kk], sc, 0, 0, 0);
            }
            // keys(r) = (r&3) + 8*(r>>2) + 4*hi; pairs r=2a,2a+1 contiguous
#pragma unroll
            for (int a = 0; a < 8; a++) {
                float p0 = EXP2F(sc[2 * a]);
                float p1 = EXP2F(sc[2 * a + 1]);
                rs += p0 + p1;
                bf16x2 pk; pk[0] = (bfr)p0; pk[1] = (bfr)p1;
                wds[ts][a] = __builtin_bit_cast(unsigned, pk);
            }
        }
        lsum += rs;

        // --- redistribute into PV B-frags: swap(w[a], w[a+2]) fills two words
        bf16x8 pfrag[4];
#pragma unroll
        for (int c = 0; c < 4; c++) {
            int ts = c >> 1, cc = c & 1;
            unsigned w0 = wds[ts][cc * 4 + 0];
            unsigned w1 = wds[ts][cc * 4 + 1];
            unsigned w2 = wds[ts][cc * 4 + 2];
            unsigned w3 = wds[ts][cc * 4 + 3];
            plswap(w0, w2);   // -> frag words 0 and 2
            plswap(w1, w3);   // -> frag words 1 and 3
            u32x4 pw; pw[0] = w0; pw[1] = w1; pw[2] = w2; pw[3] = w3;
            pfrag[c] = __builtin_bit_cast(bf16x8, pw);
        }

        // --- O^T += V^T P^T ---
#pragma unroll
        for (int kk = 0; kk < 4; kk++)
#pragma unroll
            for (int dt = 0; dt < 2; dt++) {
                int vrow = dt * 32 + l31;
                int vs = (kk * 2 + hi) ^ (vrow & 7);
                bf16x8 vf = *(const bf16x8*)(Vb + vrow * 64 + vs * 8);
                Oacc[dt] = __builtin_amdgcn_mfma_f32_32x32x16_bf16(vf, pfrag[kk], Oacc[dt], 0, 0, 0);
            }
    }
#undef STAGE

    // --- epilogue: O^T[d][q]; d = dt*32 + 8*g + 4*hi + 0..3 per lane q=qrow.
    lsum += __shfl_xor(lsum, 32);        // combine the two key-halves

    if constexpr (NSPLIT == 1) {
        float inv = 1.0f / lsum;
        float* orow = out + ((size_t)qrow * 2 + b) * HID + h * 64;
#pragma unroll
        for (int dt = 0; dt < 2; dt++)
#pragma unroll
            for (int g = 0; g < 4; g++) {
                float4 o4;
                o4.x = Oacc[dt][4 * g + 0] * inv;
                o4.y = Oacc[dt][4 * g + 1] * inv;
                o4.z = Oacc[dt][4 * g + 2] * inv;
                o4.w = Oacc[dt][4 * g + 3] * inv;
                *(float4*)(orow + dt * 32 + 8 * g + 4 * hi) = o4;
            }
    } else {
        // Write own unnormalized partial to slot [split].
        float* prow = po + (((size_t)split * 32 + hb) * S_SEQ + qrow) * 64;
#pragma unroll
        for (int dt = 0; dt < 2; dt++)
#pragma unroll
            for (int g = 0; g < 4; g++) {
                float4 o4;
                o4.x = Oacc[dt][4 * g + 0];
                o4.y = Oacc[dt][4 * g + 1];
                o4.z = Oacc[dt][4 * g + 2];
                o4.w = Oacc[dt][4 * g + 3];
                *(float4*)(prow + dt * 32 + 8 * g + 4 * hi) = o4;
            }
        if (hi == 0)
            lsumP[((size_t)split * 32 + hb) * S_SEQ + qrow] = lsum;
        __threadfence();                 // release own partial (device scope)
        __syncthreads();
        __shared__ int role;
        if (tid == 0) role = atomicAdd(&flags[hb * 16 + qt], 1);
        __syncthreads();
        if (role == 1) {                 // second finisher: combine + store
            __threadfence();             // acquire partner partial
            const float* qrow2 =
                po + (((size_t)(1 - split) * 32 + hb) * S_SEQ + qrow) * 64;
            float l2 = lsumP[((size_t)(1 - split) * 32 + hb) * S_SEQ + qrow];
            float inv = 1.0f / (lsum + l2);
            float* orow = out + ((size_t)qrow * 2 + b) * HID + h * 64;
#pragma unroll
            for (int dt = 0; dt < 2; dt++)
#pragma unroll
                for (int g = 0; g < 4; g++) {
                    int off = dt * 32 + 8 * g + 4 * hi;
                    float4 p = *(const float4*)(qrow2 + off);
                    float4 o4;
                    o4.x = (Oacc[dt][4 * g + 0] + p.x) * inv;
                    o4.y = (Oacc[dt][4 * g + 1] + p.y) * inv;
                    o4.z = (Oacc[dt][4 * g + 2] + p.z) * inv;
                    o4.w = (Oacc[dt][4 * g + 3] + p.w) * inv;
                    *(float4*)(orow + off) = o4;
                }
        }
    }
}

// ---------------------------------------------------------------------------
extern "C" void kernel_launch(void* const* d_in, const int* in_sizes, int n_in,
                              void* d_out, int out_size, void* d_ws, size_t ws_size,
                              hipStream_t stream) {
    const float* X    = (const float*)d_in[0];
    const float* W    = (const float*)d_in[1];
    const float* bias = (const float*)d_in[2];
    float* out = (float*)d_out;

    bfr* qb  = (bfr*)d_ws;
    bfr* kb  = qb + (size_t)32 * S_SEQ * 64;
    bfr* vtb = kb + (size_t)32 * S_SEQ * 64;

    // Split-K scratch (beyond the 24MB qkv region):
    //   po   [2][32][2048][64] f32 = 33.55 MB
    //   lsum [2][32][2048]     f32 =  0.52 MB
    //   flags[512]             int =  2 KB
    const size_t qkv_bytes = (size_t)3 * 32 * S_SEQ * 64 * 2;        // 25165824
    const size_t po_elems  = (size_t)2 * 32 * S_SEQ * 64;
    const size_t ls_elems  = (size_t)2 * 32 * S_SEQ;
    const size_t need = qkv_bytes + po_elems * 4 + ls_elems * 4 + 512 * 4;
    const bool use_split = ws_size >= need;

    float* po    = (float*)((char*)d_ws + qkv_bytes);
    float* lsumP = po + po_elems;
    int*   flags = (int*)(lsumP + ls_elems);

    // d_out as cast scratch (14.7 MB <= 16.8 MB); attention overwrites it last.
    bfr* Xb = (bfr*)d_out;
    bfr* Wb = Xb + (size_t)NROWS * HID;

    cast_both_kernel<<<(NROWS * HID + OUT3 * HID) / 2048, 256, 0, stream>>>(
        X, Xb, W, Wb, use_split ? flags : nullptr);

    dim3 g1(OUT3 / 128, NROWS / 128);           // 24 x 32 = 768 blocks
    qkv_gemm_mfma<<<g1, 256, 0, stream>>>(Xb, Wb, bias, qb, kb, vtb);

    if (use_split) {
        dim3 g2(S_SEQ / 64, 32);                // 32 x 32 = 1024 blocks
        attn32_kernel<2><<<g2, 256, 0, stream>>>(qb, kb, vtb, po, lsumP, flags, out);
    } else {
        dim3 g2(S_SEQ / 128, 32);               // 16 x 32 = 512 blocks
        attn32_kernel<1><<<g2, 256, 0, stream>>>(qb, kb, vtb, nullptr, nullptr, nullptr, out);
    }
}

// Round 7
// 161.756 us; speedup vs baseline: 2.4889x; 2.4795x over previous
//
#include <hip/hip_runtime.h>
#include <hip/hip_bf16.h>

// Fused QKV projection + 16-head self-attention. S=2048, B=2, H=1024, NH=16, DH=64.
// Inputs fp32, output fp32. bf16 internal compute (2% rel threshold).
//
// R19: split-K attention kept, but the combine moves OUT of the attn kernel
// into a tiny memory-bound combine_kernel. R17/R18's in-kernel combine used
// device-scope threadfence (L2 writeback/invalidate on non-coherent XCDs) +
// atomic ticket -- 1024 blocks thrashing L2 explains the 6x slowdown with all
// pipes <6% and only 100MB of HBM traffic; it also bloated the epilogue's
// register pressure (VGPR pinned at 64 regardless of launch_bounds).
// Now: attn blocks store unnormalized partial O/lsum and exit (no fence, no
// atomic -- cross-kernel visibility is stream-ordering); combine_kernel does
// out = (O0+O1)/(l0+l1), ~50MB traffic ~10us.
// Split-K math is HW-verified (R17/R18 passed, absmax 4.88e-4).
//
// d_ws: qb 8MB | kb 8MB | vtb 8MB | po[2][hb][q][d] f32 33.5MB | lsum 0.5MB

typedef __hip_bfloat16 bf16;
typedef __bf16 bfr;
typedef __attribute__((ext_vector_type(8))) __bf16 bf16x8;
typedef __attribute__((ext_vector_type(4))) __bf16 bf16x4;
typedef __attribute__((ext_vector_type(2))) __bf16 bf16x2;
typedef __attribute__((ext_vector_type(4))) float f32x4;
typedef __attribute__((ext_vector_type(16))) float f32x16;
typedef __attribute__((ext_vector_type(4))) unsigned u32x4;

#define S_SEQ  2048
#define HID    1024
#define OUT3   3072
#define NROWS  4096

#if __has_builtin(__builtin_amdgcn_exp2f)
#define EXP2F(x) __builtin_amdgcn_exp2f(x)
#else
#define EXP2F(x) exp2f(x)
#endif

// q pre-scale: (1/sqrt(64)) * log2(e) -> scores in base-2 domain
#define QSCALE 0.18033688011112042f

// ---------------------------------------------------------------------------
// Fused cast: fp32 -> bf16 for X then W (verified R9/R10).
// ---------------------------------------------------------------------------
__global__ __launch_bounds__(256) void cast_both_kernel(
    const float* __restrict__ X, bfr* __restrict__ Xb,
    const float* __restrict__ W, bfr* __restrict__ Wb)
{
    int bid = blockIdx.x;
    const float* src;
    bfr* dst;
    int lid;
    if (bid < NROWS * HID / 2048) { src = X; dst = Xb; lid = bid; }
    else { src = W; dst = Wb; lid = bid - NROWS * HID / 2048; }
    int gid = lid * 256 + threadIdx.x;
    const float4* s4 = (const float4*)src;
    float4 a = s4[(size_t)gid * 2];
    float4 b = s4[(size_t)gid * 2 + 1];
    bf16x8 v;
    v[0] = (bfr)a.x; v[1] = (bfr)a.y; v[2] = (bfr)a.z; v[3] = (bfr)a.w;
    v[4] = (bfr)b.x; v[5] = (bfr)b.y; v[6] = (bfr)b.z; v[7] = (bfr)b.w;
    *(bf16x8*)(dst + (size_t)gid * 8) = v;
}

// ---------------------------------------------------------------------------
// MFMA GEMM (m97 recipe). Epilogue: qb (pre-scaled), kb stored directly
// (32B-contiguous per 16 lanes); vtb (V^T, the 4KB-stride case) goes through
// an LDS transpose reusing the As/Bs region, then coalesced bf16x8 stores.
// ---------------------------------------------------------------------------
__device__ __forceinline__ void gload_lds16(const void* g, void* l) {
    __builtin_amdgcn_global_load_lds(
        (const __attribute__((address_space(1))) unsigned int*)g,
        (__attribute__((address_space(3))) unsigned int*)l, 16, 0, 0);
}

__global__ __launch_bounds__(256, 3) void qkv_gemm_mfma(
    const bfr* __restrict__ Xb, const bfr* __restrict__ Wb,
    const float* __restrict__ bias,
    bfr* __restrict__ qb, bfr* __restrict__ kb, bfr* __restrict__ vtb)
{
    __shared__ __attribute__((aligned(16))) unsigned char lds_all[32768];
    bfr* As = (bfr*)lds_all;              // 128x64 bf16 = 16384 B
    bfr* Bs = (bfr*)(lds_all + 16384);    // 128x64 bf16 = 16384 B
    bfr* Tr = (bfr*)lds_all;              // epilogue V^T buf: 64 x 144 = 18432 B

    const int o0 = blockIdx.x * 128;
    const int r0 = blockIdx.y * 128;
    const int tid = threadIdx.x;
    const int lane = tid & 63;
    const int w = tid >> 6;
    const int l15 = lane & 15;
    const int quad = lane >> 4;
    const int m0 = (w & 1) * 64;
    const int n0 = (w >> 1) * 64;

    f32x4 acc[4][4];
#pragma unroll
    for (int mi = 0; mi < 4; mi++)
#pragma unroll
        for (int ni = 0; ni < 4; ni++) acc[mi][ni] = {0.f, 0.f, 0.f, 0.f};

    for (int k0 = 0; k0 < HID; k0 += 64) {
#pragma unroll
        for (int i = 0; i < 4; i++) {
            int c = i * 256 + tid;
            int row = c >> 3, c8 = c & 7;
            gload_lds16(Xb + (size_t)(r0 + row) * HID + k0 + c8 * 8, As + c * 8);
            gload_lds16(Wb + (size_t)(o0 + row) * HID + k0 + c8 * 8, Bs + c * 8);
        }
        __syncthreads();

#pragma unroll
        for (int ks = 0; ks < 2; ks++) {
            bf16x8 af[4], bfg[4];
#pragma unroll
            for (int mi = 0; mi < 4; mi++)
                af[mi] = *(const bf16x8*)(As + (m0 + mi * 16 + l15) * 64 + ks * 32 + quad * 8);
#pragma unroll
            for (int ni = 0; ni < 4; ni++)
                bfg[ni] = *(const bf16x8*)(Bs + (n0 + ni * 16 + l15) * 64 + ks * 32 + quad * 8);
#pragma unroll
            for (int mi = 0; mi < 4; mi++)
#pragma unroll
                for (int ni = 0; ni < 4; ni++)
                    acc[mi][ni] = __builtin_amdgcn_mfma_f32_16x16x32_bf16(
                        af[mi], bfg[ni], acc[mi][ni], 0, 0, 0);
        }
        __syncthreads();   // also makes As/Bs safe to reuse as Tr after loop
    }

    // --- epilogue. C/D layout: col=l15, row=quad*4+r.
    const int omod = o0 % 192;
#pragma unroll
    for (int ni = 0; ni < 4; ni++) {
        int cb = o0 + n0 + ni * 16;
        int h = cb / 192;
        int rem = cb % 192;
        int t = rem >> 6;
        int d = (rem & 63) + l15;
        float bv = bias[cb + l15];
        if (t == 2) {
#pragma unroll
            for (int mi = 0; mi < 4; mi++)
#pragma unroll
                for (int r = 0; r < 4; r++) {
                    int grl = m0 + mi * 16 + quad * 4 + r;   // 0..127
                    Tr[(size_t)d * 144 + (grl & 1) * 72 + (grl >> 1)]
                        = (bfr)(acc[mi][ni][r] + bv);
                }
        } else {
#pragma unroll
            for (int mi = 0; mi < 4; mi++)
#pragma unroll
                for (int r = 0; r < 4; r++) {
                    int gr = r0 + m0 + mi * 16 + quad * 4 + r;
                    int s = gr >> 1, b = gr & 1;
                    int hb = h * 2 + b;
                    float val = acc[mi][ni][r] + bv;
                    if (t == 0)
                        qb[((size_t)hb * S_SEQ + s) * 64 + d] = (bfr)(val * QSCALE);
                    else
                        kb[((size_t)hb * S_SEQ + s) * 64 + d] = (bfr)val;
                }
        }
    }
    if (omod != 0) {          // block-uniform: this block produced a V tile
        __syncthreads();      // Tr writes visible
        int ht = (omod == 64) ? (o0 + 64) / 192 : o0 / 192;
        int d = tid >> 2;
        int b = (tid >> 1) & 1;
        int chunk = tid & 1;            // 32-s half
        int s0 = r0 >> 1;
        int hb = ht * 2 + b;
        const bfr* src = Tr + (size_t)d * 144 + b * 72 + chunk * 32;
        bfr* dstp = vtb + ((size_t)hb * 64 + d) * S_SEQ + s0 + chunk * 32;
#pragma unroll
        for (int j = 0; j < 4; j++)
            *(bf16x8*)(dstp + j * 8) = *(const bf16x8*)(src + j * 8);
    }
}

// ---------------------------------------------------------------------------
// Attention, 32x32x16 MFMA, split-K over keys: 2 blocks per (qt,hb), each
// does 16 of the 32 64-key tiles and stores an UNNORMALIZED partial.
// Block = 4 waves x 32 q = 128 q rows. Grid (32, 32) = 1024 blocks.
//   S^T = K*Q^T : A=K rows (lane&31=key), B=Q^T regs (lane&31=q).
//   C/D: col=lane&31=q, row(key)=(r&3)+8*(r>>2)+4*(lane>>5).
//   softmax in-register: exp2 + bf16 pair-pack + v_permlane32_swap_b32.
//   O^T += V^T*P^T : A=V^T rows (lane&31=d).
// LDS: 2-deep ring of {K[64][64], V^T[64][64]} bf16 = 32 KB; linear 128B rows;
// XOR swizzle slot = chunk16B ^ (row&7) on the global source AND the ds_read
// address (rule 21). Schedule per tile t: vmcnt(0); barrier; STAGE(t+1);
// compute(t). No fences/atomics: combine happens in combine_kernel
// (cross-kernel visibility = stream ordering).
// ---------------------------------------------------------------------------
__device__ __forceinline__ void plswap(unsigned &a, unsigned &b) {
    asm volatile("v_permlane32_swap_b32 %0, %1" : "+v"(a), "+v"(b));
}

__global__ __launch_bounds__(256, 2) void attn32_kernel(
    const bfr* __restrict__ qb, const bfr* __restrict__ kb,
    const bfr* __restrict__ vtb,
    float* __restrict__ po, float* __restrict__ lsumP)
{
    // [buf][K=0/V=1][row*64 + elem]; 2 * 2 * 8KB = 32KB
    __shared__ __attribute__((aligned(16))) bfr KV[2][2][64 * 64];

    constexpr int NT = 16;               // 64-key tiles per block
    const int qt    = blockIdx.x >> 1;
    const int split = blockIdx.x & 1;
    const int tbase = split * NT;
    const int hb = blockIdx.y;
    const int tid = threadIdx.x;
    const int lane = tid & 63;
    const int w = tid >> 6;
    const int l31 = lane & 31;
    const int hi = lane >> 5;
    const size_t hboff = (size_t)hb * S_SEQ * 64;

    const int srow = tid >> 3;           // staging row (0..31), +32 for i=1
    const int slot = tid & 7;            // 16B slot within the 128B row

    const int qrow = qt * 128 + w * 32 + l31;
    bf16x8 qf[4];                        // B-frags: k=d in [kk*16+hi*8, +8)
#pragma unroll
    for (int kk = 0; kk < 4; kk++)
        qf[kk] = *(const bf16x8*)(qb + hboff + (size_t)qrow * 64 + kk * 16 + hi * 8);

    f32x16 Oacc[2];
#pragma unroll
    for (int dt = 0; dt < 2; dt++)
#pragma unroll
        for (int i = 0; i < 16; i++) Oacc[dt][i] = 0.f;
    float lsum = 0.f;                    // per-lane partial (own keys only)

    // Stage local tile lt (global tile tbase+lt) into buf lt&1.
    // LDS dest linear (tid*16B); global chunk gc = slot ^ (row&7).
#define STAGE(lt_) do {                                                        \
    int lt__ = (lt_); int kt__ = tbase + lt__; int bf__ = lt__ & 1;            \
    _Pragma("unroll")                                                          \
    for (int i = 0; i < 2; i++) {                                              \
        int r = i * 32 + srow;                                                 \
        int gc = slot ^ (r & 7);                                               \
        gload_lds16(kb + hboff + (size_t)(kt__ * 64 + r) * 64 + gc * 8,        \
                    (bfr*)&KV[bf__][0][0] + i * 2048 + tid * 8);               \
    }                                                                          \
    _Pragma("unroll")                                                          \
    for (int i = 0; i < 2; i++) {                                              \
        int r = i * 32 + srow;                                                 \
        int gc = slot ^ (r & 7);                                               \
        gload_lds16(vtb + hboff + (size_t)r * S_SEQ + kt__ * 64 + gc * 8,      \
                    (bfr*)&KV[bf__][1][0] + i * 2048 + tid * 8);               \
    }                                                                          \
} while (0)

    STAGE(0);

    for (int t = 0; t < NT; t++) {
        // Loads for tile t issued one compute phase ago (prologue for t=0).
        asm volatile("s_waitcnt vmcnt(0)" ::: "memory");
        __builtin_amdgcn_s_barrier();    // + proves buf (t+1)&1 reads done
        if (t + 1 < NT) STAGE(t + 1);

        const bfr* Kb = &KV[t & 1][0][0];
        const bfr* Vb = &KV[t & 1][1][0];

        // --- S^T = K Q^T (base-2 domain), 2 key-subtiles of 32 ---
        unsigned wds[2][8];   // packed bf16 pairs
        float rs = 0.f;
#pragma unroll
        for (int ts = 0; ts < 2; ts++) {
            const int krow = ts * 32 + l31;
            f32x16 sc;
#pragma unroll
            for (int i = 0; i < 16; i++) sc[i] = 0.f;
#pragma unroll
            for (int kk = 0; kk < 4; kk++) {
                int ks = (kk * 2 + hi) ^ (krow & 7);
                bf16x8 kf = *(const bf16x8*)(Kb + krow * 64 + ks * 8);
                sc = __builtin_amdgcn_mfma_f32_32x32x16_bf16(kf, qf[kk], sc, 0, 0, 0);
            }
            // keys(r) = (r&3) + 8*(r>>2) + 4*hi; pairs r=2a,2a+1 contiguous
#pragma unroll
            for (int a = 0; a < 8; a++) {
                float p0 = EXP2F(sc[2 * a]);
                float p1 = EXP2F(sc[2 * a + 1]);
                rs += p0 + p1;
                bf16x2 pk; pk[0] = (bfr)p0; pk[1] = (bfr)p1;
                wds[ts][a] = __builtin_bit_cast(unsigned, pk);
            }
        }
        lsum += rs;

        // --- redistribute into PV B-frags: swap(w[a], w[a+2]) fills two words
        bf16x8 pfrag[4];
#pragma unroll
        for (int c = 0; c < 4; c++) {
            int ts = c >> 1, cc = c & 1;
            unsigned w0 = wds[ts][cc * 4 + 0];
            unsigned w1 = wds[ts][cc * 4 + 1];
            unsigned w2 = wds[ts][cc * 4 + 2];
            unsigned w3 = wds[ts][cc * 4 + 3];
            plswap(w0, w2);   // -> frag words 0 and 2
            plswap(w1, w3);   // -> frag words 1 and 3
            u32x4 pw; pw[0] = w0; pw[1] = w1; pw[2] = w2; pw[3] = w3;
            pfrag[c] = __builtin_bit_cast(bf16x8, pw);
        }

        // --- O^T += V^T P^T ---
#pragma unroll
        for (int kk = 0; kk < 4; kk++)
#pragma unroll
            for (int dt = 0; dt < 2; dt++) {
                int vrow = dt * 32 + l31;
                int vs = (kk * 2 + hi) ^ (vrow & 7);
                bf16x8 vf = *(const bf16x8*)(Vb + vrow * 64 + vs * 8);
                Oacc[dt] = __builtin_amdgcn_mfma_f32_32x32x16_bf16(vf, pfrag[kk], Oacc[dt], 0, 0, 0);
            }
    }
#undef STAGE

    // --- epilogue: store unnormalized partial O^T and lsum; exit. ---
    lsum += __shfl_xor(lsum, 32);        // combine the two key-half lanes

    float* prow = po + (((size_t)split * 32 + hb) * S_SEQ + qrow) * 64;
#pragma unroll
    for (int dt = 0; dt < 2; dt++)
#pragma unroll
        for (int g = 0; g < 4; g++) {
            float4 o4;
            o4.x = Oacc[dt][4 * g + 0];
            o4.y = Oacc[dt][4 * g + 1];
            o4.z = Oacc[dt][4 * g + 2];
            o4.w = Oacc[dt][4 * g + 3];
            *(float4*)(prow + dt * 32 + 8 * g + 4 * hi) = o4;
        }
    if (hi == 0)
        lsumP[((size_t)split * 32 + hb) * S_SEQ + qrow] = lsum;
}

// ---------------------------------------------------------------------------
// Combine: out[(q*2+b)*HID + h*64 + d] = (po0 + po1) / (l0 + l1).
// One thread per (hb, q, d4): 32 * 2048 * 16 = 1,048,576 threads.
// Memory-bound: 33.5MB + 1MB read, 16MB write.
// ---------------------------------------------------------------------------
__global__ __launch_bounds__(256) void combine_kernel(
    const float* __restrict__ po, const float* __restrict__ lsumP,
    float* __restrict__ out)
{
    int idx = blockIdx.x * 256 + threadIdx.x;
    int d4 = idx & 15;
    int q  = (idx >> 4) & (S_SEQ - 1);
    int hb = idx >> 15;                  // 0..31
    int h = hb >> 1, b = hb & 1;
    size_t slot = ((size_t)hb * S_SEQ + q) * 64 + d4 * 4;
    const size_t half = (size_t)32 * S_SEQ * 64;
    float4 p0 = *(const float4*)(po + slot);
    float4 p1 = *(const float4*)(po + half + slot);
    float l0 = lsumP[(size_t)hb * S_SEQ + q];
    float l1 = lsumP[(size_t)32 * S_SEQ + (size_t)hb * S_SEQ + q];
    float inv = 1.0f / (l0 + l1);
    float4 o;
    o.x = (p0.x + p1.x) * inv;
    o.y = (p0.y + p1.y) * inv;
    o.z = (p0.z + p1.z) * inv;
    o.w = (p0.w + p1.w) * inv;
    *(float4*)(out + ((size_t)q * 2 + b) * HID + h * 64 + d4 * 4) = o;
}

// ---------------------------------------------------------------------------
extern "C" void kernel_launch(void* const* d_in, const int* in_sizes, int n_in,
                              void* d_out, int out_size, void* d_ws, size_t ws_size,
                              hipStream_t stream) {
    const float* X    = (const float*)d_in[0];
    const float* W    = (const float*)d_in[1];
    const float* bias = (const float*)d_in[2];
    float* out = (float*)d_out;

    bfr* qb  = (bfr*)d_ws;
    bfr* kb  = qb + (size_t)32 * S_SEQ * 64;
    bfr* vtb = kb + (size_t)32 * S_SEQ * 64;

    // Split-K scratch (beyond the 24MB qkv region); total need ~59.2MB.
    // ws_size sufficiency HW-verified in R17/R18 (split path ran: WRITE_SIZE
    // showed the 33.5MB po traffic).
    const size_t qkv_bytes = (size_t)3 * 32 * S_SEQ * 64 * 2;        // 25165824
    const size_t po_elems  = (size_t)2 * 32 * S_SEQ * 64;
    float* po    = (float*)((char*)d_ws + qkv_bytes);
    float* lsumP = po + po_elems;

    // d_out as cast scratch (14.7 MB <= 16.8 MB); combine overwrites it last.
    bfr* Xb = (bfr*)d_out;
    bfr* Wb = Xb + (size_t)NROWS * HID;

    cast_both_kernel<<<(NROWS * HID + OUT3 * HID) / 2048, 256, 0, stream>>>(X, Xb, W, Wb);

    dim3 g1(OUT3 / 128, NROWS / 128);           // 24 x 32 = 768 blocks
    qkv_gemm_mfma<<<g1, 256, 0, stream>>>(Xb, Wb, bias, qb, kb, vtb);

    dim3 g2(S_SEQ / 64, 32);                    // 32 x 32 = 1024 blocks
    attn32_kernel<<<g2, 256, 0, stream>>>(qb, kb, vtb, po, lsumP);

    combine_kernel<<<(32 * S_SEQ * 16) / 256, 256, 0, stream>>>(po, lsumP, out);
}

// Round 10
// 157.727 us; speedup vs baseline: 2.5524x; 1.0255x over previous
//
#include <hip/hip_runtime.h>
#include <hip/hip_bf16.h>

// Fused QKV projection + 16-head self-attention. S=2048, B=2, H=1024, NH=16, DH=64.
// Inputs fp32, output fp32. bf16 internal compute (2% rel threshold).
//
// R22: restore the 5-round-proven EXP2F macro (builtin-if-available). The
// R20/R21 inline-asm v_exp_f32 experiment failed twice with the same ~6e-3
// signature (s_nop hazard fix changed nothing) and its premise was wrong:
// __builtin_amdgcn_exp2f was already native in R13-R19 (R19's VALUBusy 41%
// back-solves to native quarter-rate exp + pack/sum, not a libm surplus).
// Loop = R19's HW-validated 2-deep stage-after-barrier ring at NT=32;
// epilogue = R15's HW-validated direct normalized write.
//
// d_ws: qb[hb][s][d] 8MB | kb[hb][s][d] 8MB | vtb[hb][d][s] 8MB  (hb = h*2+b)

typedef __hip_bfloat16 bf16;
typedef __bf16 bfr;
typedef __attribute__((ext_vector_type(8))) __bf16 bf16x8;
typedef __attribute__((ext_vector_type(4))) __bf16 bf16x4;
typedef __attribute__((ext_vector_type(2))) __bf16 bf16x2;
typedef __attribute__((ext_vector_type(4))) float f32x4;
typedef __attribute__((ext_vector_type(16))) float f32x16;
typedef __attribute__((ext_vector_type(4))) unsigned u32x4;

#define S_SEQ  2048
#define HID    1024
#define OUT3   3072
#define NROWS  4096

#if __has_builtin(__builtin_amdgcn_exp2f)
#define EXP2F(x) __builtin_amdgcn_exp2f(x)
#else
#define EXP2F(x) exp2f(x)
#endif

// q pre-scale: (1/sqrt(64)) * log2(e) -> scores in base-2 domain
#define QSCALE 0.18033688011112042f

// ---------------------------------------------------------------------------
// Fused cast: fp32 -> bf16 for X then W (verified R9/R10).
// ---------------------------------------------------------------------------
__global__ __launch_bounds__(256) void cast_both_kernel(
    const float* __restrict__ X, bfr* __restrict__ Xb,
    const float* __restrict__ W, bfr* __restrict__ Wb)
{
    int bid = blockIdx.x;
    const float* src;
    bfr* dst;
    int lid;
    if (bid < NROWS * HID / 2048) { src = X; dst = Xb; lid = bid; }
    else { src = W; dst = Wb; lid = bid - NROWS * HID / 2048; }
    int gid = lid * 256 + threadIdx.x;
    const float4* s4 = (const float4*)src;
    float4 a = s4[(size_t)gid * 2];
    float4 b = s4[(size_t)gid * 2 + 1];
    bf16x8 v;
    v[0] = (bfr)a.x; v[1] = (bfr)a.y; v[2] = (bfr)a.z; v[3] = (bfr)a.w;
    v[4] = (bfr)b.x; v[5] = (bfr)b.y; v[6] = (bfr)b.z; v[7] = (bfr)b.w;
    *(bf16x8*)(dst + (size_t)gid * 8) = v;
}

// ---------------------------------------------------------------------------
// MFMA GEMM (m97 recipe). Epilogue: qb (pre-scaled), kb stored directly
// (32B-contiguous per 16 lanes); vtb (V^T, the 4KB-stride case) goes through
// an LDS transpose reusing the As/Bs region, then coalesced bf16x8 stores.
// ---------------------------------------------------------------------------
__device__ __forceinline__ void gload_lds16(const void* g, void* l) {
    __builtin_amdgcn_global_load_lds(
        (const __attribute__((address_space(1))) unsigned int*)g,
        (__attribute__((address_space(3))) unsigned int*)l, 16, 0, 0);
}

__global__ __launch_bounds__(256, 3) void qkv_gemm_mfma(
    const bfr* __restrict__ Xb, const bfr* __restrict__ Wb,
    const float* __restrict__ bias,
    bfr* __restrict__ qb, bfr* __restrict__ kb, bfr* __restrict__ vtb)
{
    __shared__ __attribute__((aligned(16))) unsigned char lds_all[32768];
    bfr* As = (bfr*)lds_all;              // 128x64 bf16 = 16384 B
    bfr* Bs = (bfr*)(lds_all + 16384);    // 128x64 bf16 = 16384 B
    bfr* Tr = (bfr*)lds_all;              // epilogue V^T buf: 64 x 144 = 18432 B

    const int o0 = blockIdx.x * 128;
    const int r0 = blockIdx.y * 128;
    const int tid = threadIdx.x;
    const int lane = tid & 63;
    const int w = tid >> 6;
    const int l15 = lane & 15;
    const int quad = lane >> 4;
    const int m0 = (w & 1) * 64;
    const int n0 = (w >> 1) * 64;

    f32x4 acc[4][4];
#pragma unroll
    for (int mi = 0; mi < 4; mi++)
#pragma unroll
        for (int ni = 0; ni < 4; ni++) acc[mi][ni] = {0.f, 0.f, 0.f, 0.f};

    for (int k0 = 0; k0 < HID; k0 += 64) {
#pragma unroll
        for (int i = 0; i < 4; i++) {
            int c = i * 256 + tid;
            int row = c >> 3, c8 = c & 7;
            gload_lds16(Xb + (size_t)(r0 + row) * HID + k0 + c8 * 8, As + c * 8);
            gload_lds16(Wb + (size_t)(o0 + row) * HID + k0 + c8 * 8, Bs + c * 8);
        }
        __syncthreads();

#pragma unroll
        for (int ks = 0; ks < 2; ks++) {
            bf16x8 af[4], bfg[4];
#pragma unroll
            for (int mi = 0; mi < 4; mi++)
                af[mi] = *(const bf16x8*)(As + (m0 + mi * 16 + l15) * 64 + ks * 32 + quad * 8);
#pragma unroll
            for (int ni = 0; ni < 4; ni++)
                bfg[ni] = *(const bf16x8*)(Bs + (n0 + ni * 16 + l15) * 64 + ks * 32 + quad * 8);
#pragma unroll
            for (int mi = 0; mi < 4; mi++)
#pragma unroll
                for (int ni = 0; ni < 4; ni++)
                    acc[mi][ni] = __builtin_amdgcn_mfma_f32_16x16x32_bf16(
                        af[mi], bfg[ni], acc[mi][ni], 0, 0, 0);
        }
        __syncthreads();   // also makes As/Bs safe to reuse as Tr after loop
    }

    // --- epilogue. C/D layout: col=l15, row=quad*4+r.
    const int omod = o0 % 192;
#pragma unroll
    for (int ni = 0; ni < 4; ni++) {
        int cb = o0 + n0 + ni * 16;
        int h = cb / 192;
        int rem = cb % 192;
        int t = rem >> 6;
        int d = (rem & 63) + l15;
        float bv = bias[cb + l15];
        if (t == 2) {
#pragma unroll
            for (int mi = 0; mi < 4; mi++)
#pragma unroll
                for (int r = 0; r < 4; r++) {
                    int grl = m0 + mi * 16 + quad * 4 + r;   // 0..127
                    Tr[(size_t)d * 144 + (grl & 1) * 72 + (grl >> 1)]
                        = (bfr)(acc[mi][ni][r] + bv);
                }
        } else {
#pragma unroll
            for (int mi = 0; mi < 4; mi++)
#pragma unroll
                for (int r = 0; r < 4; r++) {
                    int gr = r0 + m0 + mi * 16 + quad * 4 + r;
                    int s = gr >> 1, b = gr & 1;
                    int hb = h * 2 + b;
                    float val = acc[mi][ni][r] + bv;
                    if (t == 0)
                        qb[((size_t)hb * S_SEQ + s) * 64 + d] = (bfr)(val * QSCALE);
                    else
                        kb[((size_t)hb * S_SEQ + s) * 64 + d] = (bfr)val;
                }
        }
    }
    if (omod != 0) {          // block-uniform: this block produced a V tile
        __syncthreads();      // Tr writes visible
        int ht = (omod == 64) ? (o0 + 64) / 192 : o0 / 192;
        int d = tid >> 2;
        int b = (tid >> 1) & 1;
        int chunk = tid & 1;            // 32-s half
        int s0 = r0 >> 1;
        int hb = ht * 2 + b;
        const bfr* src = Tr + (size_t)d * 144 + b * 72 + chunk * 32;
        bfr* dstp = vtb + ((size_t)hb * 64 + d) * S_SEQ + s0 + chunk * 32;
#pragma unroll
        for (int j = 0; j < 4; j++)
            *(bf16x8*)(dstp + j * 8) = *(const bf16x8*)(src + j * 8);
    }
}

// ---------------------------------------------------------------------------
// Attention, 32x32x16 MFMA, single-pass (32 key-tiles per block).
// Block = 4 waves x 32 q = 128 q rows, one hb. Grid (16, 32) = 512 blocks.
//   S^T = K*Q^T : A=K rows (lane&31=key), B=Q^T regs (lane&31=q).
//   C/D: col=lane&31=q, row(key)=(r&3)+8*(r>>2)+4*(lane>>5).
//   softmax in-register: EXP2F + bf16 pair-pack + permlane32_swap.
//   O^T += V^T*P^T : A=V^T rows (lane&31=d).
// LDS: 2-deep ring of {K[64][64], V^T[64][64]} bf16 = 32 KB; linear 128B rows;
// XOR swizzle slot = chunk16B ^ (row&7) on the global source AND the ds_read
// address (rule 21). Schedule per tile t: vmcnt(0); barrier; STAGE(t+1);
// compute(t) -- the vmcnt waits on loads issued one full compute phase ago.
// (Ring + schedule HW-validated in R19; epilogue HW-validated in R15.)
// ---------------------------------------------------------------------------
__device__ __forceinline__ void plswap(unsigned &a, unsigned &b) {
    asm volatile("v_permlane32_swap_b32 %0, %1" : "+v"(a), "+v"(b));
}

__global__ __launch_bounds__(256, 2) void attn32_kernel(
    const bfr* __restrict__ qb, const bfr* __restrict__ kb,
    const bfr* __restrict__ vtb, float* __restrict__ out)
{
    // [buf][K=0/V=1][row*64 + elem]; 2 * 2 * 8KB = 32KB
    __shared__ __attribute__((aligned(16))) bfr KV[2][2][64 * 64];

    constexpr int NT = 32;               // 64-key tiles per block
    const int qt = blockIdx.x;
    const int hb = blockIdx.y;
    const int h = hb >> 1, b = hb & 1;
    const int tid = threadIdx.x;
    const int lane = tid & 63;
    const int w = tid >> 6;
    const int l31 = lane & 31;
    const int hi = lane >> 5;
    const size_t hboff = (size_t)hb * S_SEQ * 64;

    const int srow = tid >> 3;           // staging row (0..31), +32 for i=1
    const int slot = tid & 7;            // 16B slot within the 128B row

    const int qrow = qt * 128 + w * 32 + l31;
    bf16x8 qf[4];                        // B-frags: k=d in [kk*16+hi*8, +8)
#pragma unroll
    for (int kk = 0; kk < 4; kk++)
        qf[kk] = *(const bf16x8*)(qb + hboff + (size_t)qrow * 64 + kk * 16 + hi * 8);

    f32x16 Oacc[2];
#pragma unroll
    for (int dt = 0; dt < 2; dt++)
#pragma unroll
        for (int i = 0; i < 16; i++) Oacc[dt][i] = 0.f;
    float lsum = 0.f;                    // per-lane partial (own keys only)

    // Stage tile t into buf t&1. LDS dest linear (tid*16B); global chunk
    // gc = slot ^ (row&7)  (inverse-swizzled source).
#define STAGE(t_) do {                                                         \
    int kt__ = (t_); int bf__ = kt__ & 1;                                      \
    _Pragma("unroll")                                                          \
    for (int i = 0; i < 2; i++) {                                              \
        int r = i * 32 + srow;                                                 \
        int gc = slot ^ (r & 7);                                               \
        gload_lds16(kb + hboff + (size_t)(kt__ * 64 + r) * 64 + gc * 8,        \
                    (bfr*)&KV[bf__][0][0] + i * 2048 + tid * 8);               \
    }                                                                          \
    _Pragma("unroll")                                                          \
    for (int i = 0; i < 2; i++) {                                              \
        int r = i * 32 + srow;                                                 \
        int gc = slot ^ (r & 7);                                               \
        gload_lds16(vtb + hboff + (size_t)r * S_SEQ + kt__ * 64 + gc * 8,      \
                    (bfr*)&KV[bf__][1][0] + i * 2048 + tid * 8);               \
    }                                                                          \
} while (0)

    STAGE(0);

    for (int t = 0; t < NT; t++) {
        // Loads for tile t issued one compute phase ago (prologue for t=0).
        asm volatile("s_waitcnt vmcnt(0)" ::: "memory");
        __builtin_amdgcn_s_barrier();    // + proves buf (t+1)&1 reads done
        if (t + 1 < NT) STAGE(t + 1);

        const bfr* Kb = &KV[t & 1][0][0];
        const bfr* Vb = &KV[t & 1][1][0];

        // --- S^T = K Q^T (base-2 domain), 2 key-subtiles of 32 ---
        unsigned wds[2][8];   // packed bf16 pairs
        float rs = 0.f;
#pragma unroll
        for (int ts = 0; ts < 2; ts++) {
            const int krow = ts * 32 + l31;
            f32x16 sc;
#pragma unroll
            for (int i = 0; i < 16; i++) sc[i] = 0.f;
#pragma unroll
            for (int kk = 0; kk < 4; kk++) {
                int ks = (kk * 2 + hi) ^ (krow & 7);
                bf16x8 kf = *(const bf16x8*)(Kb + krow * 64 + ks * 8);
                sc = __builtin_amdgcn_mfma_f32_32x32x16_bf16(kf, qf[kk], sc, 0, 0, 0);
            }
            // keys(r) = (r&3) + 8*(r>>2) + 4*hi; pairs r=2a,2a+1 contiguous
#pragma unroll
            for (int a = 0; a < 8; a++) {
                float p0 = EXP2F(sc[2 * a]);
                float p1 = EXP2F(sc[2 * a + 1]);
                rs += p0 + p1;
                bf16x2 pk; pk[0] = (bfr)p0; pk[1] = (bfr)p1;
                wds[ts][a] = __builtin_bit_cast(unsigned, pk);
            }
        }
        lsum += rs;

        // --- redistribute into PV B-frags: swap(w[a], w[a+2]) fills two words
        bf16x8 pfrag[4];
#pragma unroll
        for (int c = 0; c < 4; c++) {
            int ts = c >> 1, cc = c & 1;
            unsigned w0 = wds[ts][cc * 4 + 0];
            unsigned w1 = wds[ts][cc * 4 + 1];
            unsigned w2 = wds[ts][cc * 4 + 2];
            unsigned w3 = wds[ts][cc * 4 + 3];
            plswap(w0, w2);   // -> frag words 0 and 2
            plswap(w1, w3);   // -> frag words 1 and 3
            u32x4 pw; pw[0] = w0; pw[1] = w1; pw[2] = w2; pw[3] = w3;
            pfrag[c] = __builtin_bit_cast(bf16x8, pw);
        }

        // --- O^T += V^T P^T ---
#pragma unroll
        for (int kk = 0; kk < 4; kk++)
#pragma unroll
            for (int dt = 0; dt < 2; dt++) {
                int vrow = dt * 32 + l31;
                int vs = (kk * 2 + hi) ^ (vrow & 7);
                bf16x8 vf = *(const bf16x8*)(Vb + vrow * 64 + vs * 8);
                Oacc[dt] = __builtin_amdgcn_mfma_f32_32x32x16_bf16(vf, pfrag[kk], Oacc[dt], 0, 0, 0);
            }
    }
#undef STAGE

    // --- epilogue: O^T[d][q] -> out[s][b][h*64+d], float4 stores ---
    lsum += __shfl_xor(lsum, 32);        // combine the two key-half lanes
    float inv = 1.0f / lsum;
    float* orow = out + ((size_t)qrow * 2 + b) * HID + h * 64;
#pragma unroll
    for (int dt = 0; dt < 2; dt++)
#pragma unroll
        for (int g = 0; g < 4; g++) {
            float4 o4;
            o4.x = Oacc[dt][4 * g + 0] * inv;
            o4.y = Oacc[dt][4 * g + 1] * inv;
            o4.z = Oacc[dt][4 * g + 2] * inv;
            o4.w = Oacc[dt][4 * g + 3] * inv;
            *(float4*)(orow + dt * 32 + 8 * g + 4 * hi) = o4;
        }
}

// ---------------------------------------------------------------------------
extern "C" void kernel_launch(void* const* d_in, const int* in_sizes, int n_in,
                              void* d_out, int out_size, void* d_ws, size_t ws_size,
                              hipStream_t stream) {
    const float* X    = (const float*)d_in[0];
    const float* W    = (const float*)d_in[1];
    const float* bias = (const float*)d_in[2];
    float* out = (float*)d_out;

    bfr* qb  = (bfr*)d_ws;
    bfr* kb  = qb + (size_t)32 * S_SEQ * 64;
    bfr* vtb = kb + (size_t)32 * S_SEQ * 64;

    // d_out as cast scratch (14.7 MB <= 16.8 MB); attention overwrites it last.
    bfr* Xb = (bfr*)d_out;
    bfr* Wb = Xb + (size_t)NROWS * HID;

    cast_both_kernel<<<(NROWS * HID + OUT3 * HID) / 2048, 256, 0, stream>>>(X, Xb, W, Wb);

    dim3 g1(OUT3 / 128, NROWS / 128);           // 24 x 32 = 768 blocks
    qkv_gemm_mfma<<<g1, 256, 0, stream>>>(Xb, Wb, bias, qb, kb, vtb);

    dim3 g2(S_SEQ / 128, 32);                   // 16 x 32 = 512 blocks
    attn32_kernel<<<g2, 256, 0, stream>>>(qb, kb, vtb, out);
}